// Round 5
// baseline (4912.363 us; speedup 1.0000x reference)
//
#include <hip/hip_runtime.h>
#include <hip/hip_cooperative_groups.h>

typedef short s16x8 __attribute__((ext_vector_type(8)));
typedef float f32x4 __attribute__((ext_vector_type(4)));
typedef float f32x2 __attribute__((ext_vector_type(2)));
typedef unsigned int u32x4 __attribute__((ext_vector_type(4)));
typedef unsigned int u32x2 __attribute__((ext_vector_type(2)));

#define B_ 64
#define T_ 512
#define D_ 1024
#define H_ 1024
#define TC_ 128   // time chunk

__device__ __forceinline__ unsigned short f2bf(float f) {
  union { float f; unsigned int u; } v; v.f = f;
  unsigned int r = v.u + 0x7fffu + ((v.u >> 16) & 1u);
  return (unsigned short)(r >> 16);
}
__device__ __forceinline__ float bf2f(unsigned short h) {
  union { unsigned int u; float f; } v; v.u = ((unsigned int)h) << 16;
  return v.f;
}

// ---- convert W_ih and W_hh fp32 -> bf16 (n = 3*1024*1024 each) ----
__global__ __launch_bounds__(256) void k_cvt_w(const float* __restrict__ w1, unsigned short* __restrict__ o1,
                                               const float* __restrict__ w2, unsigned short* __restrict__ o2) {
  int i = (blockIdx.x * 256 + threadIdx.x) * 4;
  float4 a = *(const float4*)(w1 + i);
  u32x2 p;
  p.x = (unsigned)f2bf(a.x) | ((unsigned)f2bf(a.y) << 16);
  p.y = (unsigned)f2bf(a.z) | ((unsigned)f2bf(a.w) << 16);
  *(u32x2*)(o1 + i) = p;
  float4 b = *(const float4*)(w2 + i);
  u32x2 q;
  q.x = (unsigned)f2bf(b.x) | ((unsigned)f2bf(b.y) << 16);
  q.y = (unsigned)f2bf(b.z) | ((unsigned)f2bf(b.w) << 16);
  *(u32x2*)(o2 + i) = q;
}

// ---- x [B][T][D] fp32 -> xt [(tl*64+b)][D] bf16 for t in [t0, t0+TC_) ----
__global__ __launch_bounds__(256) void k_xt(const float* __restrict__ x, unsigned short* __restrict__ xt, int t0) {
  int m = blockIdx.x;              // m = tl*64 + b
  int t = t0 + (m >> 6), b = m & 63;
  const float* src = x + ((size_t)(b * T_ + t)) * D_;
  unsigned short* dst = xt + (size_t)m * D_;
  int d = threadIdx.x * 4;
  float4 a = *(const float4*)(src + d);
  u32x2 p;
  p.x = (unsigned)f2bf(a.x) | ((unsigned)f2bf(a.y) << 16);
  p.y = (unsigned)f2bf(a.z) | ((unsigned)f2bf(a.w) << 16);
  *(u32x2*)(dst + d) = p;
}

// ---- h0 -> hb16[slot0] (bf16 [b][k], pre-masked for t=0) + hchk (fp32); maskT; zero grp ----
__global__ __launch_bounds__(256) void k_misc(const float* __restrict__ h0, const int* __restrict__ dones,
                                              unsigned short* __restrict__ hb16, float* __restrict__ hchk,
                                              float* __restrict__ maskT, unsigned int* __restrict__ grp) {
  int i = blockIdx.x * 256 + threadIdx.x;  // 65536 = B*H
  int b = i >> 10;
  float v = h0[i];
  hchk[i] = v;
  int m0 = dones[b * T_];                  // dones[b][0]: h zeroed before consuming step 0
  hb16[i] = m0 ? (unsigned short)0 : f2bf(v);
  if (i < T_ * B_) {
    int t = i >> 6, bb = i & 63;
    maskT[i] = dones[bb * T_ + t] ? 0.f : 1.f;
  }
  if (i < 8) grp[i * 64] = 0u;             // 8 group counters, 256B apart
}

// ---- gi = xt @ W_ih^T + b_ih ; A[8192][1024], B[3072][1024], C[m][n] bf16 ----
__global__ __launch_bounds__(256) void k_gemm(const unsigned short* __restrict__ A,
                                              const unsigned short* __restrict__ Bm,
                                              const float* __restrict__ bias,
                                              unsigned short* __restrict__ C) {
  __shared__ __align__(16) unsigned short As[128 * 40];
  __shared__ __align__(16) unsigned short Bs[128 * 40];
  const int tid = threadIdx.x;
  const int wave = tid >> 6, lane = tid & 63;
  const int q = lane >> 4, r = lane & 15;
  const int wm = wave >> 1, wn = wave & 1;
  const long m0 = (long)blockIdx.y * 128, n0 = (long)blockIdx.x * 128;
  f32x4 acc[4][4] = {};
  for (int k0 = 0; k0 < 1024; k0 += 32) {
    __syncthreads();
#pragma unroll
    for (int c0 = 0; c0 < 2; ++c0) {
      int c = c0 * 256 + tid;
      int row = c >> 2, kof = (c & 3) * 8;
      *(u32x4*)&As[row * 40 + kof] = *(const u32x4*)(A + (m0 + row) * 1024 + k0 + kof);
      *(u32x4*)&Bs[row * 40 + kof] = *(const u32x4*)(Bm + (n0 + row) * 1024 + k0 + kof);
    }
    __syncthreads();
    s16x8 af[4], bfr[4];
#pragma unroll
    for (int mt = 0; mt < 4; ++mt)
      af[mt] = *(const s16x8*)&As[(wm * 64 + mt * 16 + r) * 40 + q * 8];
#pragma unroll
    for (int nt = 0; nt < 4; ++nt)
      bfr[nt] = *(const s16x8*)&Bs[(wn * 64 + nt * 16 + r) * 40 + q * 8];
#pragma unroll
    for (int mt = 0; mt < 4; ++mt)
#pragma unroll
      for (int nt = 0; nt < 4; ++nt)
        acc[mt][nt] = __builtin_amdgcn_mfma_f32_16x16x32_bf16(af[mt], bfr[nt], acc[mt][nt], 0, 0, 0);
  }
#pragma unroll
  for (int nt = 0; nt < 4; ++nt) {
    long n = n0 + wn * 64 + nt * 16 + r;
    float bn = bias[n];
#pragma unroll
    for (int mt = 0; mt < 4; ++mt) {
#pragma unroll
      for (int reg = 0; reg < 4; ++reg) {
        long m = m0 + wm * 64 + mt * 16 + q * 4 + reg;
        C[m * 3072 + n] = f2bf(acc[mt][nt][reg] + bn);
      }
    }
  }
}

// ---- persistent recurrent kernel: 64 blocks x 512 threads (8 waves) ----
// Dataflow sync: wave w consumes h-cols [128w,128w+128) produced by blocks 8w..8w+7;
// it polls grp[w] >= 8*t, then loads its MFMA A-frags with MALL-direct (sc0 sc1) loads.
// Producer publishes via plain stores + release-RMW on grp[bid>>3] (wbl2 -> MALL).
// No grid barrier, no L2 invalidate, no LDS h-staging.
// r5 fix: A-frag loads split into single-instruction asm with "=&v" early-clobber
// (r4 had 4 loads in one asm block with plain "=v": allocator could overlap an output
// tuple with the address pair -> load 0's return clobbers loads 1-3's address -> fault).
__global__ __launch_bounds__(512) void k_gru(const unsigned short* __restrict__ whh,
                                             const float* __restrict__ bhh,
                                             const unsigned short* __restrict__ gi,
                                             const float* __restrict__ maskT,
                                             unsigned short* __restrict__ hb16,
                                             float* __restrict__ hchk,
                                             float* __restrict__ out,
                                             unsigned int* __restrict__ grp,
                                             int t0) {
  __shared__ __align__(16) float red[3 * 8 * 16 * 68];  // 104448 B kp-reduce buffer
  const int tid = threadIdx.x;
  const int w = tid >> 6, lane = tid & 63;
  const int q = lane >> 4, r = lane & 15;
  const int j0 = blockIdx.x * 16;
  float* hlast = out + (size_t)B_ * T_ * H_;

  // B-frags resident in VGPRs: Wreg[g][ks] lane(q,r) = W[g*1024+j0+r][w*128+ks*32+q*8 ..+8]
  s16x8 Wreg[3][4];
#pragma unroll
  for (int g = 0; g < 3; ++g)
#pragma unroll
    for (int ks = 0; ks < 4; ++ks)
      Wreg[g][ks] = *(const s16x8*)(whh + ((size_t)(g * 1024 + j0 + r)) * 1024 + w * 128 + ks * 32 + q * 8);

  // epilogue cells: (b0+e, c=j0+r), e in {0,1}; b0 = w*8 + q*2
  const int b0 = w * 8 + q * 2;
  const float bh0 = bhh[j0 + r];
  const float bh1 = bhh[1024 + j0 + r];
  const float bh2 = bhh[2048 + j0 + r];
  float hreg[2];
  hreg[0] = hchk[(size_t)b0 * 1024 + j0 + r];
  hreg[1] = hchk[(size_t)(b0 + 1) * 1024 + j0 + r];

  // A-frag row byte-offsets within one h slot: row (bt*16+r), k-base w*128 + q*8 shorts
  unsigned rowoff[4];
#pragma unroll
  for (int bt = 0; bt < 4; ++bt)
    rowoff[bt] = (unsigned)((bt * 16 + r) * 2048 + w * 256 + q * 16);

  unsigned int* gw = grp + w * 64;          // this wave's producer-group counter
  unsigned int* gmine = grp + (blockIdx.x >> 3) * 64;

  f32x4 acc[3][4] = {};
  float gcur[6], gnxt[6], mcur[2], mnxt[2], mncur[2], mnnxt[2];
#pragma unroll
  for (int e = 0; e < 2; ++e) {  // preload tl=0
    size_t mrow = (size_t)(b0 + e) * 3072;
    gcur[e * 3 + 0] = bf2f(gi[mrow + j0 + r]);
    gcur[e * 3 + 1] = bf2f(gi[mrow + 1024 + j0 + r]);
    gcur[e * 3 + 2] = bf2f(gi[mrow + 2048 + j0 + r]);
    mcur[e] = maskT[t0 * 64 + b0 + e];
    int tn = (t0 + 1 < 512) ? t0 + 1 : 511;
    mncur[e] = maskT[tn * 64 + b0 + e];
  }

  for (int tl = 0; tl < TC_; ++tl) {
    const int t = t0 + tl;
    const unsigned long long hs64 = (unsigned long long)(hb16 + (size_t)(t & 1) * 65536);
    unsigned short* hd = hb16 + (size_t)((t + 1) & 1) * 65536;

    // 1) poll: my k-slice producers (blocks 8w..8w+7) must have finished step t-1
    {
      const unsigned tgt = 8u * (unsigned)t;
      while (__hip_atomic_load(gw, __ATOMIC_RELAXED, __HIP_MEMORY_SCOPE_AGENT) < tgt)
        __builtin_amdgcn_s_sleep(1);
    }

    // 2) A-frags direct from MALL (sc0 sc1 bypasses stale L1/L2) — no inv needed
    s16x8 fa[4][4];
#pragma unroll
    for (int bt = 0; bt < 4; ++bt) {
      unsigned long long av = hs64 + rowoff[bt];
      asm volatile("global_load_dwordx4 %0, %1, off sc0 sc1"
                   : "=&v"(fa[bt][0]) : "v"(av) : "memory");
      asm volatile("global_load_dwordx4 %0, %1, off offset:64 sc0 sc1"
                   : "=&v"(fa[bt][1]) : "v"(av) : "memory");
      asm volatile("global_load_dwordx4 %0, %1, off offset:128 sc0 sc1"
                   : "=&v"(fa[bt][2]) : "v"(av) : "memory");
      asm volatile("global_load_dwordx4 %0, %1, off offset:192 sc0 sc1"
                   : "=&v"(fa[bt][3]) : "v"(av) : "memory");
    }
    asm volatile("s_waitcnt vmcnt(0)" ::: "memory");
    __builtin_amdgcn_sched_barrier(0);

    // 3) matvec: fa[bt][ks] x Wreg[g][ks] -> acc[g][bt]
#pragma unroll
    for (int ks = 0; ks < 4; ++ks)
#pragma unroll
      for (int g = 0; g < 3; ++g)
#pragma unroll
        for (int bt = 0; bt < 4; ++bt)
          acc[g][bt] = __builtin_amdgcn_mfma_f32_16x16x32_bf16(fa[bt][ks], Wreg[g][ks], acc[g][bt], 0, 0, 0);

    // 4) kp-partials -> LDS (prev step's reads are behind last iter's post-epilogue barrier)
#pragma unroll
    for (int g = 0; g < 3; ++g)
#pragma unroll
      for (int bt = 0; bt < 4; ++bt) {
        *(f32x4*)&red[(size_t)((g * 8 + w) * 16 + r) * 68 + bt * 16 + q * 4] = acc[g][bt];
        acc[g][bt] = (f32x4){0.f, 0.f, 0.f, 0.f};
      }
    __syncthreads();

    // 5) epilogue: sum over kp, gate math, store next-step (pre-masked) bf16 h
    f32x2 ps[3];
#pragma unroll
    for (int g = 0; g < 3; ++g) {
      f32x2 s = {0.f, 0.f};
#pragma unroll
      for (int kp = 0; kp < 8; ++kp)
        s += *(const f32x2*)&red[(size_t)((g * 8 + kp) * 16 + r) * 68 + b0];
      ps[g] = s;
    }
    float hn2[2];
#pragma unroll
    for (int e = 0; e < 2; ++e) {
      float ghr = ps[0][e] + bh0;
      float ghz = ps[1][e] + bh1;
      float ghn = ps[2][e] + bh2;
      float rr = 1.f / (1.f + __expf(-(gcur[e * 3 + 0] + ghr)));
      float zz = 1.f / (1.f + __expf(-(gcur[e * 3 + 1] + ghz)));
      float nn = tanhf(gcur[e * 3 + 2] + rr * ghn);
      float hp = hreg[e] * mcur[e];
      float hn = (1.f - zz) * nn + zz * hp;
      hreg[e] = hn;
      hn2[e] = hn;
      unsigned short hv = (mncur[e] == 0.f) ? (unsigned short)0 : f2bf(hn);
      hd[(size_t)(b0 + e) * 1024 + j0 + r] = hv;   // plain store; release wbl2 publishes
    }
    __syncthreads();  // drains vmcnt: all waves' h stores are in L2

    // 6) publish: release flushes L2 (on-die, to MALL) then bumps my group counter
    if (tid == 0)
      __hip_atomic_fetch_add(gmine, 1u, __ATOMIC_RELEASE, __HIP_MEMORY_SCOPE_AGENT);

    // 7) overlap: out stores + chunk-boundary stores + next-step gi/mask prefetch
#pragma unroll
    for (int e = 0; e < 2; ++e) {
      int b = b0 + e;
      out[((size_t)b * 512 + t) * 1024 + j0 + r] = hn2[e];
      if (t == 511) hlast[(size_t)b * 1024 + j0 + r] = hn2[e];
      if (tl == TC_ - 1) hchk[(size_t)b * 1024 + j0 + r] = hn2[e];
    }
    if (tl + 1 < TC_) {  // gi/maskT immutable during kernel: stale-cache safe
#pragma unroll
      for (int e = 0; e < 2; ++e) {
        size_t mrow = (size_t)((tl + 1) * 64 + b0 + e) * 3072;
        gnxt[e * 3 + 0] = bf2f(gi[mrow + j0 + r]);
        gnxt[e * 3 + 1] = bf2f(gi[mrow + 1024 + j0 + r]);
        gnxt[e * 3 + 2] = bf2f(gi[mrow + 2048 + j0 + r]);
        mnxt[e] = maskT[(t + 1) * 64 + b0 + e];
        int tn = (t + 2 < 512) ? t + 2 : 511;
        mnnxt[e] = maskT[tn * 64 + b0 + e];
      }
#pragma unroll
      for (int e = 0; e < 2; ++e) {
        gcur[e * 3 + 0] = gnxt[e * 3 + 0];
        gcur[e * 3 + 1] = gnxt[e * 3 + 1];
        gcur[e * 3 + 2] = gnxt[e * 3 + 2];
        mcur[e] = mnxt[e];
        mncur[e] = mnnxt[e];
      }
    }
  }
}

extern "C" void kernel_launch(void* const* d_in, const int* in_sizes, int n_in,
                              void* d_out, int out_size, void* d_ws, size_t ws_size,
                              hipStream_t stream) {
  const float* x     = (const float*)d_in[0];
  const float* h0    = (const float*)d_in[1];
  const int*   dones = (const int*)d_in[2];
  const float* Wih   = (const float*)d_in[3];
  const float* Whh   = (const float*)d_in[4];
  const float* bih   = (const float*)d_in[5];
  const float* bhh   = (const float*)d_in[6];
  float* out = (float*)d_out;
  char* ws = (char*)d_ws;
  // ws layout:
  unsigned short* wih_b = (unsigned short*)(ws);                  //  6 MB   [0, 6291456)
  unsigned short* whh_b = (unsigned short*)(ws + 6291456);        //  6 MB   [6291456, 12582912)
  unsigned short* xt_c  = (unsigned short*)(ws + 12582912);       // 16 MB   [12582912, 29360128)
  unsigned short* gi_c  = (unsigned short*)(ws + 29360128);       // 48 MB   [29360128, 79691776)
  float*          maskT = (float*)(ws + 79691776);                // 128 KB  [79691776, 79822848)
  unsigned short* hb16  = (unsigned short*)(ws + 79822848);       // 256 KB  h double buffer [b][k]
  float*          hchk  = (float*)(ws + 80085248);                // 256 KB  [80085248, 80347392)
  unsigned int*   grp   = (unsigned int*)(ws + 80347392);         // 2 KB    8 counters, 256B stride

  k_cvt_w<<<3072, 256, 0, stream>>>(Wih, wih_b, Whh, whh_b);
  k_misc<<<256, 256, 0, stream>>>(h0, dones, hb16, hchk, maskT, grp);

  for (int c = 0; c < 4; ++c) {
    int t0 = c * TC_;
    k_xt<<<TC_ * 64, 256, 0, stream>>>(x, xt_c, t0);
    k_gemm<<<dim3(24, TC_ * 64 / 128), 256, 0, stream>>>(xt_c, wih_b, bih, gi_c);
    void* args[] = {(void*)&whh_b, (void*)&bhh, (void*)&gi_c, (void*)&maskT,
                    (void*)&hb16, (void*)&hchk, (void*)&out, (void*)&grp, (void*)&t0};
    hipLaunchCooperativeKernel((const void*)k_gru, dim3(64), dim3(512), args, 0, stream);
  }
}

// Round 6
// 3843.547 us; speedup vs baseline: 1.2781x; 1.2781x over previous
//
#include <hip/hip_runtime.h>
#include <hip/hip_cooperative_groups.h>

typedef short s16x8 __attribute__((ext_vector_type(8)));
typedef float f32x4 __attribute__((ext_vector_type(4)));
typedef float f32x2 __attribute__((ext_vector_type(2)));
typedef unsigned int u32x4 __attribute__((ext_vector_type(4)));
typedef unsigned int u32x2 __attribute__((ext_vector_type(2)));

#define B_ 64
#define T_ 512
#define D_ 1024
#define H_ 1024
#define TC_ 128   // time chunk

__device__ __forceinline__ unsigned short f2bf(float f) {
  union { float f; unsigned int u; } v; v.f = f;
  unsigned int r = v.u + 0x7fffu + ((v.u >> 16) & 1u);
  return (unsigned short)(r >> 16);
}
__device__ __forceinline__ float bf2f(unsigned short h) {
  union { unsigned int u; float f; } v; v.u = ((unsigned int)h) << 16;
  return v.f;
}

// ---- convert W_ih and W_hh fp32 -> bf16 (n = 3*1024*1024 each) ----
__global__ __launch_bounds__(256) void k_cvt_w(const float* __restrict__ w1, unsigned short* __restrict__ o1,
                                               const float* __restrict__ w2, unsigned short* __restrict__ o2) {
  int i = (blockIdx.x * 256 + threadIdx.x) * 4;
  float4 a = *(const float4*)(w1 + i);
  u32x2 p;
  p.x = (unsigned)f2bf(a.x) | ((unsigned)f2bf(a.y) << 16);
  p.y = (unsigned)f2bf(a.z) | ((unsigned)f2bf(a.w) << 16);
  *(u32x2*)(o1 + i) = p;
  float4 b = *(const float4*)(w2 + i);
  u32x2 q;
  q.x = (unsigned)f2bf(b.x) | ((unsigned)f2bf(b.y) << 16);
  q.y = (unsigned)f2bf(b.z) | ((unsigned)f2bf(b.w) << 16);
  *(u32x2*)(o2 + i) = q;
}

// ---- x [B][T][D] fp32 -> xt [(tl*64+b)][D] bf16 for t in [t0, t0+TC_) ----
__global__ __launch_bounds__(256) void k_xt(const float* __restrict__ x, unsigned short* __restrict__ xt, int t0) {
  int m = blockIdx.x;              // m = tl*64 + b
  int t = t0 + (m >> 6), b = m & 63;
  const float* src = x + ((size_t)(b * T_ + t)) * D_;
  unsigned short* dst = xt + (size_t)m * D_;
  int d = threadIdx.x * 4;
  float4 a = *(const float4*)(src + d);
  u32x2 p;
  p.x = (unsigned)f2bf(a.x) | ((unsigned)f2bf(a.y) << 16);
  p.y = (unsigned)f2bf(a.z) | ((unsigned)f2bf(a.w) << 16);
  *(u32x2*)(dst + d) = p;
}

// ---- h0 -> hb16[slot0] (bf16 [b][k], pre-masked for t=0) + hchk (fp32); maskT; zero grp ----
__global__ __launch_bounds__(256) void k_misc(const float* __restrict__ h0, const int* __restrict__ dones,
                                              unsigned short* __restrict__ hb16, float* __restrict__ hchk,
                                              float* __restrict__ maskT, unsigned int* __restrict__ grp) {
  int i = blockIdx.x * 256 + threadIdx.x;  // 65536 = B*H
  int b = i >> 10;
  float v = h0[i];
  hchk[i] = v;
  int m0 = dones[b * T_];                  // dones[b][0]: h zeroed before consuming step 0
  hb16[i] = m0 ? (unsigned short)0 : f2bf(v);
  if (i < T_ * B_) {
    int t = i >> 6, bb = i & 63;
    maskT[i] = dones[bb * T_ + t] ? 0.f : 1.f;
  }
  if (i < 8) grp[i * 64] = 0u;             // 8 group counters, 256B apart
}

// ---- gi = xt @ W_ih^T + b_ih ; A[8192][1024], B[3072][1024], C[m][n] bf16 ----
__global__ __launch_bounds__(256) void k_gemm(const unsigned short* __restrict__ A,
                                              const unsigned short* __restrict__ Bm,
                                              const float* __restrict__ bias,
                                              unsigned short* __restrict__ C) {
  __shared__ __align__(16) unsigned short As[128 * 40];
  __shared__ __align__(16) unsigned short Bs[128 * 40];
  const int tid = threadIdx.x;
  const int wave = tid >> 6, lane = tid & 63;
  const int q = lane >> 4, r = lane & 15;
  const int wm = wave >> 1, wn = wave & 1;
  const long m0 = (long)blockIdx.y * 128, n0 = (long)blockIdx.x * 128;
  f32x4 acc[4][4] = {};
  for (int k0 = 0; k0 < 1024; k0 += 32) {
    __syncthreads();
#pragma unroll
    for (int c0 = 0; c0 < 2; ++c0) {
      int c = c0 * 256 + tid;
      int row = c >> 2, kof = (c & 3) * 8;
      *(u32x4*)&As[row * 40 + kof] = *(const u32x4*)(A + (m0 + row) * 1024 + k0 + kof);
      *(u32x4*)&Bs[row * 40 + kof] = *(const u32x4*)(Bm + (n0 + row) * 1024 + k0 + kof);
    }
    __syncthreads();
    s16x8 af[4], bfr[4];
#pragma unroll
    for (int mt = 0; mt < 4; ++mt)
      af[mt] = *(const s16x8*)&As[(wm * 64 + mt * 16 + r) * 40 + q * 8];
#pragma unroll
    for (int nt = 0; nt < 4; ++nt)
      bfr[nt] = *(const s16x8*)&Bs[(wn * 64 + nt * 16 + r) * 40 + q * 8];
#pragma unroll
    for (int mt = 0; mt < 4; ++mt)
#pragma unroll
      for (int nt = 0; nt < 4; ++nt)
        acc[mt][nt] = __builtin_amdgcn_mfma_f32_16x16x32_bf16(af[mt], bfr[nt], acc[mt][nt], 0, 0, 0);
  }
#pragma unroll
  for (int nt = 0; nt < 4; ++nt) {
    long n = n0 + wn * 64 + nt * 16 + r;
    float bn = bias[n];
#pragma unroll
    for (int mt = 0; mt < 4; ++mt) {
#pragma unroll
      for (int reg = 0; reg < 4; ++reg) {
        long m = m0 + wm * 64 + mt * 16 + q * 4 + reg;
        C[m * 3072 + n] = f2bf(acc[mt][nt][reg] + bn);
      }
    }
  }
}

// ---- persistent recurrent kernel: 64 blocks x 512 threads (8 waves) ----
// Dataflow sync: wave w consumes h-cols [128w,128w+128) produced by blocks 8w..8w+7.
// r6: publish path has ZERO cache maintenance. h is stored with sc0 sc1
// (write-through to MALL, globally visible at vmcnt retire); after vmcnt(0)+
// syncthreads the group counter is bumped with a RELAXED RMW (no buffer_wbl2 —
// r3/r5 both paid a per-step RELEASE -> L2 writeback walk on the critical path).
// Consumers: relaxed poll + sc0 sc1 MALL-direct loads (unchanged from r5).
__global__ __launch_bounds__(512) void k_gru(const unsigned short* __restrict__ whh,
                                             const float* __restrict__ bhh,
                                             const unsigned short* __restrict__ gi,
                                             const float* __restrict__ maskT,
                                             unsigned short* __restrict__ hb16,
                                             float* __restrict__ hchk,
                                             float* __restrict__ out,
                                             unsigned int* __restrict__ grp,
                                             int t0) {
  __shared__ __align__(16) float red[3 * 8 * 16 * 68];  // 104448 B kp-reduce buffer
  const int tid = threadIdx.x;
  const int w = tid >> 6, lane = tid & 63;
  const int q = lane >> 4, r = lane & 15;
  const int j0 = blockIdx.x * 16;
  float* hlast = out + (size_t)B_ * T_ * H_;

  // B-frags resident in VGPRs: Wreg[g][ks] lane(q,r) = W[g*1024+j0+r][w*128+ks*32+q*8 ..+8]
  s16x8 Wreg[3][4];
#pragma unroll
  for (int g = 0; g < 3; ++g)
#pragma unroll
    for (int ks = 0; ks < 4; ++ks)
      Wreg[g][ks] = *(const s16x8*)(whh + ((size_t)(g * 1024 + j0 + r)) * 1024 + w * 128 + ks * 32 + q * 8);

  // epilogue cells: (b0+e, c=j0+r), e in {0,1}; b0 = w*8 + q*2
  const int b0 = w * 8 + q * 2;
  const float bh0 = bhh[j0 + r];
  const float bh1 = bhh[1024 + j0 + r];
  const float bh2 = bhh[2048 + j0 + r];
  float hreg[2];
  hreg[0] = hchk[(size_t)b0 * 1024 + j0 + r];
  hreg[1] = hchk[(size_t)(b0 + 1) * 1024 + j0 + r];

  // A-frag row byte-offsets within one h slot: row (bt*16+r), k-base w*128 + q*8 shorts
  unsigned rowoff[4];
#pragma unroll
  for (int bt = 0; bt < 4; ++bt)
    rowoff[bt] = (unsigned)((bt * 16 + r) * 2048 + w * 256 + q * 16);

  unsigned int* gw = grp + w * 64;          // this wave's producer-group counter
  unsigned int* gmine = grp + (blockIdx.x >> 3) * 64;

  f32x4 acc[3][4] = {};
  float gcur[6], gnxt[6], mcur[2], mnxt[2], mncur[2], mnnxt[2];
#pragma unroll
  for (int e = 0; e < 2; ++e) {  // preload tl=0
    size_t mrow = (size_t)(b0 + e) * 3072;
    gcur[e * 3 + 0] = bf2f(gi[mrow + j0 + r]);
    gcur[e * 3 + 1] = bf2f(gi[mrow + 1024 + j0 + r]);
    gcur[e * 3 + 2] = bf2f(gi[mrow + 2048 + j0 + r]);
    mcur[e] = maskT[t0 * 64 + b0 + e];
    int tn = (t0 + 1 < 512) ? t0 + 1 : 511;
    mncur[e] = maskT[tn * 64 + b0 + e];
  }

  for (int tl = 0; tl < TC_; ++tl) {
    const int t = t0 + tl;
    const unsigned long long hs64 = (unsigned long long)(hb16 + (size_t)(t & 1) * 65536);
    unsigned short* hd = hb16 + (size_t)((t + 1) & 1) * 65536;

    // 1) poll: my k-slice producers (blocks 8w..8w+7) must have finished step t-1
    {
      const unsigned tgt = 8u * (unsigned)t;
      while (__hip_atomic_load(gw, __ATOMIC_RELAXED, __HIP_MEMORY_SCOPE_AGENT) < tgt)
        __builtin_amdgcn_s_sleep(1);
    }

    // 2) A-frags direct from MALL (sc0 sc1 bypasses stale L1/L2) — no inv needed
    s16x8 fa[4][4];
#pragma unroll
    for (int bt = 0; bt < 4; ++bt) {
      unsigned long long av = hs64 + rowoff[bt];
      asm volatile("global_load_dwordx4 %0, %1, off sc0 sc1"
                   : "=&v"(fa[bt][0]) : "v"(av) : "memory");
      asm volatile("global_load_dwordx4 %0, %1, off offset:64 sc0 sc1"
                   : "=&v"(fa[bt][1]) : "v"(av) : "memory");
      asm volatile("global_load_dwordx4 %0, %1, off offset:128 sc0 sc1"
                   : "=&v"(fa[bt][2]) : "v"(av) : "memory");
      asm volatile("global_load_dwordx4 %0, %1, off offset:192 sc0 sc1"
                   : "=&v"(fa[bt][3]) : "v"(av) : "memory");
    }
    asm volatile("s_waitcnt vmcnt(0)" ::: "memory");
    __builtin_amdgcn_sched_barrier(0);

    // 3) matvec: fa[bt][ks] x Wreg[g][ks] -> acc[g][bt]
#pragma unroll
    for (int ks = 0; ks < 4; ++ks)
#pragma unroll
      for (int g = 0; g < 3; ++g)
#pragma unroll
        for (int bt = 0; bt < 4; ++bt)
          acc[g][bt] = __builtin_amdgcn_mfma_f32_16x16x32_bf16(fa[bt][ks], Wreg[g][ks], acc[g][bt], 0, 0, 0);

    // 4) kp-partials -> LDS (prev step's reads are behind last iter's post-epilogue barrier)
#pragma unroll
    for (int g = 0; g < 3; ++g)
#pragma unroll
      for (int bt = 0; bt < 4; ++bt) {
        *(f32x4*)&red[(size_t)((g * 8 + w) * 16 + r) * 68 + bt * 16 + q * 4] = acc[g][bt];
        acc[g][bt] = (f32x4){0.f, 0.f, 0.f, 0.f};
      }
    __syncthreads();

    // 5) epilogue: sum over kp, gate math; h stores go MALL-direct (sc0 sc1 write-through)
    f32x2 ps[3];
#pragma unroll
    for (int g = 0; g < 3; ++g) {
      f32x2 s = {0.f, 0.f};
#pragma unroll
      for (int kp = 0; kp < 8; ++kp)
        s += *(const f32x2*)&red[(size_t)((g * 8 + kp) * 16 + r) * 68 + b0];
      ps[g] = s;
    }
    float hn2[2];
#pragma unroll
    for (int e = 0; e < 2; ++e) {
      float ghr = ps[0][e] + bh0;
      float ghz = ps[1][e] + bh1;
      float ghn = ps[2][e] + bh2;
      float rr = 1.f / (1.f + __expf(-(gcur[e * 3 + 0] + ghr)));
      float zz = 1.f / (1.f + __expf(-(gcur[e * 3 + 1] + ghz)));
      float nn = tanhf(gcur[e * 3 + 2] + rr * ghn);
      float hp = hreg[e] * mcur[e];
      float hn = (1.f - zz) * nn + zz * hp;
      hreg[e] = hn;
      hn2[e] = hn;
      unsigned short hv = (mncur[e] == 0.f) ? (unsigned short)0 : f2bf(hn);
      unsigned long long ha = (unsigned long long)(hd + (size_t)(b0 + e) * 1024 + j0 + r);
      unsigned int hw32 = (unsigned int)hv;
      asm volatile("global_store_short %0, %1, off sc0 sc1"
                   :: "v"(ha), "v"(hw32) : "memory");
    }
    asm volatile("s_waitcnt vmcnt(0)" ::: "memory");  // h at MALL (coherence point)
    __syncthreads();                                   // all waves' h at MALL

    // 6) publish: RELAXED RMW — counter and data are both already at MALL; no wbl2
    if (tid == 0)
      __hip_atomic_fetch_add(gmine, 1u, __ATOMIC_RELAXED, __HIP_MEMORY_SCOPE_AGENT);

    // 7) overlap: out stores + chunk-boundary stores + next-step gi/mask prefetch
#pragma unroll
    for (int e = 0; e < 2; ++e) {
      int b = b0 + e;
      out[((size_t)b * 512 + t) * 1024 + j0 + r] = hn2[e];
      if (t == 511) hlast[(size_t)b * 1024 + j0 + r] = hn2[e];
      if (tl == TC_ - 1) hchk[(size_t)b * 1024 + j0 + r] = hn2[e];
    }
    if (tl + 1 < TC_) {  // gi/maskT immutable during kernel: stale-cache safe
#pragma unroll
      for (int e = 0; e < 2; ++e) {
        size_t mrow = (size_t)((tl + 1) * 64 + b0 + e) * 3072;
        gnxt[e * 3 + 0] = bf2f(gi[mrow + j0 + r]);
        gnxt[e * 3 + 1] = bf2f(gi[mrow + 1024 + j0 + r]);
        gnxt[e * 3 + 2] = bf2f(gi[mrow + 2048 + j0 + r]);
        mnxt[e] = maskT[(t + 1) * 64 + b0 + e];
        int tn = (t + 2 < 512) ? t + 2 : 511;
        mnnxt[e] = maskT[tn * 64 + b0 + e];
      }
#pragma unroll
      for (int e = 0; e < 2; ++e) {
        gcur[e * 3 + 0] = gnxt[e * 3 + 0];
        gcur[e * 3 + 1] = gnxt[e * 3 + 1];
        gcur[e * 3 + 2] = gnxt[e * 3 + 2];
        mcur[e] = mnxt[e];
        mncur[e] = mnnxt[e];
      }
    }
  }
}

extern "C" void kernel_launch(void* const* d_in, const int* in_sizes, int n_in,
                              void* d_out, int out_size, void* d_ws, size_t ws_size,
                              hipStream_t stream) {
  const float* x     = (const float*)d_in[0];
  const float* h0    = (const float*)d_in[1];
  const int*   dones = (const int*)d_in[2];
  const float* Wih   = (const float*)d_in[3];
  const float* Whh   = (const float*)d_in[4];
  const float* bih   = (const float*)d_in[5];
  const float* bhh   = (const float*)d_in[6];
  float* out = (float*)d_out;
  char* ws = (char*)d_ws;
  // ws layout:
  unsigned short* wih_b = (unsigned short*)(ws);                  //  6 MB   [0, 6291456)
  unsigned short* whh_b = (unsigned short*)(ws + 6291456);        //  6 MB   [6291456, 12582912)
  unsigned short* xt_c  = (unsigned short*)(ws + 12582912);       // 16 MB   [12582912, 29360128)
  unsigned short* gi_c  = (unsigned short*)(ws + 29360128);       // 48 MB   [29360128, 79691776)
  float*          maskT = (float*)(ws + 79691776);                // 128 KB  [79691776, 79822848)
  unsigned short* hb16  = (unsigned short*)(ws + 79822848);       // 256 KB  h double buffer [b][k]
  float*          hchk  = (float*)(ws + 80085248);                // 256 KB  [80085248, 80347392)
  unsigned int*   grp   = (unsigned int*)(ws + 80347392);         // 2 KB    8 counters, 256B stride

  k_cvt_w<<<3072, 256, 0, stream>>>(Wih, wih_b, Whh, whh_b);
  k_misc<<<256, 256, 0, stream>>>(h0, dones, hb16, hchk, maskT, grp);

  for (int c = 0; c < 4; ++c) {
    int t0 = c * TC_;
    k_xt<<<TC_ * 64, 256, 0, stream>>>(x, xt_c, t0);
    k_gemm<<<dim3(24, TC_ * 64 / 128), 256, 0, stream>>>(xt_c, wih_b, bih, gi_c);
    void* args[] = {(void*)&whh_b, (void*)&bhh, (void*)&gi_c, (void*)&maskT,
                    (void*)&hb16, (void*)&hchk, (void*)&out, (void*)&grp, (void*)&t0};
    hipLaunchCooperativeKernel((const void*)k_gru, dim3(64), dim3(512), args, 0, stream);
  }
}